// Round 11
// baseline (173.270 us; speedup 1.0000x reference)
//
#include <hip/hip_runtime.h>
#include <hip/hip_bf16.h>
#include <hip/hip_fp16.h>

#define NTOK 16384
#define HDIM 2048
#define NEXP 128
#define KSEL 8
#define NCAND 16
#define DELTA_GAP 4e-3f     // single-product fp16: gap-err sigma ~5.1e-4 -> 7.8 sigma
#define LO_SCALE 2048.0f
#define LO_INV (1.0f/2048.0f)

typedef _Float16 half8  __attribute__((ext_vector_type(8)));
typedef float    f32x4  __attribute__((ext_vector_type(4)));

// ===========================================================================
// Kernel 0: W fp32 -> fragment-major fp16 HI plane only (512 KB, L2-hot).
// Fragment (ks, eg): halfword index ((ks*8 + eg)*64 + l)*8 + j holds
// w[16*eg + (l&15)][32*ks + 8*(l>>4) + j]  (layout proven rounds 4-10).
// ===========================================================================
__global__ __launch_bounds__(256) void w_convert(
    const float* __restrict__ w, _Float16* __restrict__ whp)
{
    const int e = blockIdx.x;            // 0..127
    const int k = threadIdx.x * 8;       // 0..2040
    const float* src = w + (size_t)e * HDIM + k;
    const f32x4 v0 = *reinterpret_cast<const f32x4*>(src);
    const f32x4 v1 = *reinterpret_cast<const f32x4*>(src + 4);
    half8 h;
#pragma unroll
    for (int j = 0; j < 4; ++j) {
        h[j]     = (_Float16)v0[j];
        h[4 + j] = (_Float16)v1[j];
    }
    const int ks = k >> 5;
    const int eg = e >> 4;
    const int l  = (e & 15) | (((k >> 3) & 3) << 4);
    *reinterpret_cast<half8*>(whp + ((size_t)(ks * 8 + eg) * 64 + l) * 8) = h;
}

// ===========================================================================
// Kernel 1: single-product fp16 MFMA GEMM, NO LDS / NO barriers in K-loop.
// Grid 1024 blocks x 256 thr = 4 waves; wave = 16 tokens x 128 experts x one
// K-quarter (512 k = 16 steps of 32). B fragments load DIRECTLY from the
// fragment-major hi plane into registers (L2-hot, 1-step prefetch, plain C —
// compiler-counted waits). A direct from global, 1-step prefetch. ~136 VGPR
// -> 3 waves/SIMD (12 waves/CU): TLP hides L2/HBM latency (m97 regime).
// Epilogue: one 32KB LDS pass for cross-q reduce (1 barrier), then top-16
// selection + gap certification (DELTA=4e-3) + top-8 probs per token.
// ===========================================================================
__global__ __launch_bounds__(256, 3) void gemm1_fused(
    const float* __restrict__ x, const _Float16* __restrict__ whp,
    float* __restrict__ logits, float* __restrict__ topv, float* __restrict__ topi,
    int* __restrict__ cand, int* __restrict__ flag)
{
    __shared__ f32x4 red[4][8][64];   // [q][eg][lane] = 32 KB

    const int tid = threadIdx.x;
    const int l   = tid & 63;
    const int q   = tid >> 6;         // wave = K-quarter 0..3
    const int t0  = blockIdx.x * 16;

    // A: lane covers token row t0+(l&15), k-octet 8*(l>>4) within each 32-k step
    const float* xrow = x + (size_t)(t0 + (l & 15)) * HDIM + q * 512 + 8 * (l >> 4);
    // B: this wave's K-quarter of the fragment-major plane
    const _Float16* wq = whp + (size_t)q * 16 * 8 * 512;

    f32x4 acc[8];
#pragma unroll
    for (int eg = 0; eg < 8; ++eg) acc[eg] = (f32x4){0.f, 0.f, 0.f, 0.f};

#define LOADA(A, S)                                                        \
    {                                                                      \
        A[0] = *reinterpret_cast<const f32x4*>(xrow + (S) * 32);           \
        A[1] = *reinterpret_cast<const f32x4*>(xrow + (S) * 32 + 4);       \
    }
#define LOADB(B, S)                                                        \
    {                                                                      \
        _Pragma("unroll")                                                  \
        for (int eg_ = 0; eg_ < 8; ++eg_)                                  \
            B[eg_] = *reinterpret_cast<const half8*>(                      \
                wq + ((size_t)(S) * 8 + eg_) * 512 + l * 8);               \
    }
#define CVTA(AH, A)                                                        \
    {                                                                      \
        _Pragma("unroll")                                                  \
        for (int j_ = 0; j_ < 4; ++j_) {                                   \
            AH[j_]     = (_Float16)A[0][j_];                               \
            AH[4 + j_] = (_Float16)A[1][j_];                               \
        }                                                                  \
    }
#define MFMA8(AH, B)                                                       \
    {                                                                      \
        _Pragma("unroll")                                                  \
        for (int eg_ = 0; eg_ < 8; ++eg_)                                  \
            acc[eg_] = __builtin_amdgcn_mfma_f32_16x16x32_f16(             \
                AH, B[eg_], acc[eg_], 0, 0, 0);                            \
    }

    f32x4 a0[2], a1[2];
    half8 b0[8], b1[8];

    LOADA(a0, 0) LOADB(b0, 0)
    for (int s = 0; s < 16; s += 2) {
        LOADA(a1, s + 1) LOADB(b1, s + 1)   // next step in flight during compute
        {
            half8 ah; CVTA(ah, a0) MFMA8(ah, b0)
        }
        if (s + 2 < 16) { LOADA(a0, s + 2) LOADB(b0, s + 2) }
        {
            half8 ah; CVTA(ah, a1) MFMA8(ah, b1)
        }
    }
#undef LOADA
#undef LOADB
#undef CVTA
#undef MFMA8

    // ---- cross-q reduction: one LDS pass, fixed order (deterministic) ----
#pragma unroll
    for (int eg = 0; eg < 8; ++eg)
        red[q][eg][l] = acc[eg];
    __syncthreads();

    f32x4 v[8];
#pragma unroll
    for (int eg = 0; eg < 8; ++eg) {
        f32x4 s0 = red[0][eg][l];
        s0 += red[1][eg][l];
        s0 += red[2][eg][l];
        s0 += red[3][eg][l];
        v[eg] = s0;
    }

    // ---- this wave handles token row rr = q of each 4-row group ----
    const int grp  = l >> 4;
    const int ln16 = l & 15;
    const int t    = t0 + 4 * grp + q;
    const float NEG = -__builtin_inff();

    float vr[8];
#pragma unroll
    for (int f = 0; f < 8; ++f) {
        const f32x4 t4 = v[f];
        vr[f] = (q == 0) ? t4[0] : (q == 1) ? t4[1] : (q == 2) ? t4[2] : t4[3];
        logits[(size_t)t * NEXP + 16 * f + ln16] = vr[f];
    }

    unsigned selm = 0u;
    int   mycand = 0;
    float mycv   = 0.0f;
#pragma unroll
    for (int k = 0; k < NCAND; ++k) {
        float lv = NEG; int le = 0;
#pragma unroll
        for (int f = 0; f < 8; ++f) {
            const float c = ((selm >> f) & 1u) ? NEG : vr[f];
            if (c > lv) { lv = c; le = 16 * f + ln16; }   // asc f => lower id on tie
        }
        float cv = lv; int ce = le;
#pragma unroll
        for (int off = 8; off > 0; off >>= 1) {
            const float ov = __shfl_xor(cv, off, 16);
            const int   oe = __shfl_xor(ce, off, 16);
            if (ov > cv || (ov == cv && oe < ce)) { cv = ov; ce = oe; }
        }
        if (ln16 == k) { mycand = ce; mycv = cv; }
        if ((ce & 15) == ln16) selm |= 1u << (ce >> 4);
    }

    // gap certification over ranks 0..8
    const float nv = __shfl(mycv, ln16 + 1, 16);
    int fl = (ln16 <= 8 && (mycv - nv) < DELTA_GAP) ? 1 : 0;
#pragma unroll
    for (int off = 8; off > 0; off >>= 1)
        fl |= __shfl_xor(fl, off, 16);

    // normalized top-8 probs (softmax denom cancels in renorm)
    const float m = __shfl(mycv, 0, 16);
    const float p = (ln16 < KSEL) ? expf(mycv - m) : 0.0f;
    float ps = p;
#pragma unroll
    for (int off = 8; off > 0; off >>= 1)
        ps += __shfl_xor(ps, off, 16);

    cand[(size_t)t * NCAND + ln16] = mycand;
    if (ln16 < KSEL) {
        topv[(size_t)t * KSEL + ln16] = p / ps;
        topi[(size_t)t * KSEL + ln16] = (float)mycand;
    }
    if (ln16 == 0) flag[t] = fl;
}

// ===========================================================================
// Kernel 2: fp64 refine of flagged tokens (~2-3K expected at DELTA=4e-3).
// One wave per token; unflagged waves exit at the flag read.
// ===========================================================================
__global__ __launch_bounds__(256) void refine_flagged(
    const float* __restrict__ x, const float* __restrict__ w,
    const int* __restrict__ cand, const int* __restrict__ flag,
    float* __restrict__ topv, float* __restrict__ topi)
{
    const int l = threadIdx.x & 63;
    const int t = (int)((blockIdx.x * 256u + threadIdx.x) >> 6);
    if (!flag[t]) return;   // wave-uniform

    const int myid = cand[(size_t)t * NCAND + (l & 15)];
    const float* xrow = x + (size_t)t * HDIM;

    double xd[32];
#pragma unroll
    for (int i = 0; i < 8; ++i) {
        const f32x4 xv = *reinterpret_cast<const f32x4*>(xrow + i * 256 + l * 4);
#pragma unroll
        for (int j = 0; j < 4; ++j) xd[i * 4 + j] = (double)xv[j];
    }

    double part[NCAND];
    int    cid[NCAND];
#pragma unroll
    for (int c = 0; c < NCAND; ++c) {
        const int eid = __shfl(myid, c);
        cid[c] = eid;
        const float* wrow = w + (size_t)eid * HDIM;
        double s = 0.0;
#pragma unroll
        for (int i = 0; i < 8; ++i) {
            const f32x4 wv4 = *reinterpret_cast<const f32x4*>(wrow + i * 256 + l * 4);
#pragma unroll
            for (int j = 0; j < 4; ++j)
                s = fma(xd[i * 4 + j], (double)wv4[j], s);
        }
        part[c] = s;
    }

#pragma unroll
    for (int off = 32; off > 0; off >>= 1)
#pragma unroll
        for (int c = 0; c < NCAND; ++c)
            part[c] += __shfl_xor(part[c], off);

    unsigned selm = 0u;
    double m = 0.0, kv = 0.0;
    int ki = 0;
    float psum = 0.0f;
#pragma unroll
    for (int k = 0; k < KSEL; ++k) {
        double bv = -__builtin_inf(); int bi = 0x7fffffff; int bc = 0;
#pragma unroll
        for (int c = 0; c < NCAND; ++c) {
            if (!((selm >> c) & 1u)) {
                if (part[c] > bv || (part[c] == bv && cid[c] < bi)) {
                    bv = part[c]; bi = cid[c]; bc = c;
                }
            }
        }
        if (k == 0) m = bv;
        psum += expf((float)(bv - m));
        if (l == k) { kv = bv; ki = bi; }
        selm |= 1u << bc;
    }

    if (l < KSEL) {
        topv[(size_t)t * KSEL + l] = expf((float)(kv - m)) / psum;
        topi[(size_t)t * KSEL + l] = (float)ki;
    }
}

// ===========================================================================
// Fallback (ws too small): proven round-2 fused fp64 kernel.
// ===========================================================================
#define BM 64
#define BK 32
#define BSTRIDE (BK + 4)
__global__ __launch_bounds__(256) void router_fused(
    const float* __restrict__ x, const float* __restrict__ w,
    float* __restrict__ logits, float* __restrict__ topv, float* __restrict__ topi)
{
    __shared__ float Bs[NEXP][BSTRIDE];
    const int tid = threadIdx.x;
    const int tn = tid & 15, tm = tid >> 4;
    const int row0 = blockIdx.x * BM;
    const int kc = tid & 7, cr = tid >> 3;

    double acc[4][8];
#pragma unroll
    for (int i = 0; i < 4; ++i)
#pragma unroll
        for (int j = 0; j < 8; ++j) acc[i][j] = 0.0;

    const float* xp[4];
#pragma unroll
    for (int i = 0; i < 4; ++i) xp[i] = x + (size_t)(row0 + tm + 16 * i) * HDIM;

    float4 rb[4];
#pragma unroll
    for (int p = 0; p < 4; ++p)
        rb[p] = *reinterpret_cast<const float4*>(&w[(size_t)(cr + 32 * p) * HDIM + kc * 4]);

    for (int k0 = 0; k0 < HDIM; k0 += BK) {
        __syncthreads();
#pragma unroll
        for (int p = 0; p < 4; ++p)
            *reinterpret_cast<float4*>(&Bs[cr + 32 * p][kc * 4]) = rb[p];
        __syncthreads();
        if (k0 + BK < HDIM) {
#pragma unroll
            for (int p = 0; p < 4; ++p)
                rb[p] = *reinterpret_cast<const float4*>(
                    &w[(size_t)(cr + 32 * p) * HDIM + (k0 + BK) + kc * 4]);
        }
#pragma unroll 4
        for (int k4 = 0; k4 < BK; k4 += 4) {
            float4 a4[4], b4[8];
#pragma unroll
            for (int i = 0; i < 4; ++i)
                a4[i] = *reinterpret_cast<const float4*>(&xp[i][k0 + k4]);
#pragma unroll
            for (int j = 0; j < 8; ++j)
                b4[j] = *reinterpret_cast<const float4*>(&Bs[tn + 16 * j][k4]);
#pragma unroll
            for (int kk = 0; kk < 4; ++kk) {
                double bd[8];
#pragma unroll
                for (int j = 0; j < 8; ++j) bd[j] = (double)((const float*)&b4[j])[kk];
#pragma unroll
                for (int i = 0; i < 4; ++i) {
                    const double ad = (double)((const float*)&a4[i])[kk];
#pragma unroll
                    for (int j = 0; j < 8; ++j) acc[i][j] = fma(ad, bd[j], acc[i][j]);
                }
            }
        }
    }
#pragma unroll
    for (int i = 0; i < 4; ++i) {
        float* orow = logits + (size_t)(row0 + tm + 16 * i) * NEXP;
#pragma unroll
        for (int j = 0; j < 8; ++j) orow[tn + 16 * j] = (float)acc[i][j];
    }
    for (int i = 0; i < 4; ++i) {
        const int t = row0 + tm + 16 * i;
        unsigned sel = 0u;
        double m = 0.0, kv = 0.0;
        int ki = 0;
        const double NEGD = -__builtin_inf();
#pragma unroll
        for (int k = 0; k < KSEL; ++k) {
            double lv = NEGD; int le = 0;
#pragma unroll
            for (int j = 0; j < 8; ++j) {
                const double v = (sel >> j) & 1u ? NEGD : acc[i][j];
                if (v > lv) { lv = v; le = tn + 16 * j; }
            }
            double cv = lv; int ce = le;
#pragma unroll
            for (int off = 8; off > 0; off >>= 1) {
                const double ov = __shfl_xor(cv, off, 16);
                const int    oe = __shfl_xor(ce, off, 16);
                if (ov > cv || (ov == cv && oe < ce)) { cv = ov; ce = oe; }
            }
            if (k == 0) m = cv;
            if (tn == k) { kv = cv; ki = ce; }
            if ((ce & 15) == tn) sel |= 1u << (ce >> 4);
        }
        float z = 0.0f;
#pragma unroll
        for (int j = 0; j < 8; ++j) z += expf((float)(acc[i][j] - m));
#pragma unroll
        for (int off = 8; off > 0; off >>= 1) z += __shfl_xor(z, off, 16);
        const float p = (tn < KSEL) ? expf((float)(kv - m)) / z : 0.0f;
        float ps = p;
#pragma unroll
        for (int off = 8; off > 0; off >>= 1) ps += __shfl_xor(ps, off, 16);
        if (tn < KSEL) {
            topv[(size_t)t * KSEL + tn] = p / ps;
            topi[(size_t)t * KSEL + tn] = (float)ki;
        }
    }
}

extern "C" void kernel_launch(void* const* d_in, const int* in_sizes, int n_in,
                              void* d_out, int out_size, void* d_ws, size_t ws_size,
                              hipStream_t stream) {
    const float* x = (const float*)d_in[0];   // [16384, 2048]
    const float* w = (const float*)d_in[1];   // [128, 2048]

    float* out    = (float*)d_out;
    float* logits = out;                                   // 16384*128
    float* topv   = out + (size_t)NTOK * NEXP;             // 16384*8
    float* topi   = topv + (size_t)NTOK * KSEL;            // 16384*8

    // ws layout: whp[512KB] | cand[1MB] | flag[64KB]
    const size_t plane = (size_t)NEXP * HDIM;              // 262144 halfwords
    const size_t need  = plane * sizeof(_Float16)
                       + (size_t)NTOK * NCAND * sizeof(int)
                       + (size_t)NTOK * sizeof(int);
    if (ws_size >= need) {
        _Float16* whp = (_Float16*)d_ws;
        int* cand = (int*)(whp + plane);
        int* flag = cand + (size_t)NTOK * NCAND;
        w_convert<<<NEXP, 256, 0, stream>>>(w, whp);
        gemm1_fused<<<NTOK / 16, 256, 0, stream>>>(x, whp, logits, topv, topi, cand, flag);
        refine_flagged<<<NTOK / 4, 256, 0, stream>>>(x, w, cand, flag, topv, topi);
    } else {
        router_fused<<<NTOK / BM, 256, 0, stream>>>(x, w, logits, topv, topi);
    }
}

// Round 12
// 81.567 us; speedup vs baseline: 2.1243x; 2.1243x over previous
//
#include <hip/hip_runtime.h>
#include <hip/hip_bf16.h>
#include <hip/hip_fp16.h>

#define NTOK 16384
#define HDIM 2048
#define NEXP 128
#define KSEL 8
#define NCAND 16
#define DELTA_GAP 1e-4f     // 3-product err sigma ~1e-6 << DELTA/6; proven R5-R10
#define LO_SCALE 2048.0f    // 2^11: keeps lo-planes in fp16 normal range
#define LO_INV (1.0f/2048.0f)

typedef _Float16 half8  __attribute__((ext_vector_type(8)));
typedef float    f32x4  __attribute__((ext_vector_type(4)));

// ===========================================================================
// Kernel 0: W fp32 -> fragment-major fp16 hi/lo planes (once, 1 MB, L2-hot).
// Fragment (ks, eg): halfword index ((ks*8 + eg)*64 + l)*8 + j holds
// w[16*eg + (l&15)][32*ks + 8*(l>>4) + j]  (layout proven rounds 4-11).
// ===========================================================================
__global__ __launch_bounds__(256) void w_convert(
    const float* __restrict__ w, _Float16* __restrict__ whp, _Float16* __restrict__ wlp)
{
    const int e = blockIdx.x;            // 0..127
    const int k = threadIdx.x * 8;       // 0..2040
    const float* src = w + (size_t)e * HDIM + k;
    const f32x4 v0 = *reinterpret_cast<const f32x4*>(src);
    const f32x4 v1 = *reinterpret_cast<const f32x4*>(src + 4);
    float vv[8] = {v0[0], v0[1], v0[2], v0[3], v1[0], v1[1], v1[2], v1[3]};
    half8 h, lo;
#pragma unroll
    for (int j = 0; j < 8; ++j) {
        const _Float16 hj = (_Float16)vv[j];
        h[j]  = hj;
        lo[j] = (_Float16)((vv[j] - (float)hj) * LO_SCALE);
    }
    const int ks = k >> 5;
    const int eg = e >> 4;
    const int l  = (e & 15) | (((k >> 3) & 3) << 4);
    const size_t di = ((size_t)(ks * 8 + eg) * 64 + l) * 8;
    *reinterpret_cast<half8*>(whp + di) = h;
    *reinterpret_cast<half8*>(wlp + di) = lo;
}

// ===========================================================================
// Kernel 1: split-fp16 3-product MFMA GEMM in the R11 no-LDS structure.
// Grid 512 x 256 thr = 4 waves; wave = 32 tokens (2 M-subtiles) x 128 experts
// x one K-quarter (512 k = 16 steps of 32). B fragments (hi+lo) load DIRECTLY
// from the fragment-major planes into registers (L2-hot, same addrs across
// all blocks); A direct from global with 1-step prefetch. No LDS / barriers
// in the K-loop; plain-C loads = compiler-counted waits; 2 waves/SIMD TLP.
// Epilogue: 64KB LDS cross-q reduce (1 barrier) + proven R7/R8 distributed
// top-16 / certify(1e-4) / top-8 epilogue.
// ===========================================================================
__global__ __launch_bounds__(256, 2) void gemm3_nolds(
    const float* __restrict__ x,
    const _Float16* __restrict__ whp, const _Float16* __restrict__ wlp,
    float* __restrict__ logits, float* __restrict__ topv, float* __restrict__ topi,
    int* __restrict__ cand, int* __restrict__ flag)
{
    __shared__ f32x4 red[4][2][8][64];   // [q][ms][eg][lane] = 64 KB

    const int tid = threadIdx.x;
    const int l   = tid & 63;
    const int q   = tid >> 6;            // wave = K-quarter 0..3
    const int t0  = blockIdx.x * 32;

    // A: lane covers rows t0+(l&15) / +16, k-octet 8*(l>>4) per 32-k step
    const float* xrow0 = x + (size_t)(t0 + (l & 15)) * HDIM + q * 512 + 8 * (l >> 4);
    const float* xrow1 = xrow0 + (size_t)16 * HDIM;
    // B: this wave's K-quarter of the fragment-major planes [s][eg][512]
    const _Float16* wqh = whp + (size_t)q * 16 * 8 * 512;
    const _Float16* wql = wlp + (size_t)q * 16 * 8 * 512;

    f32x4 acc[2][8], acc2[2][8];
#pragma unroll
    for (int ms = 0; ms < 2; ++ms)
#pragma unroll
        for (int eg = 0; eg < 8; ++eg) {
            acc[ms][eg]  = (f32x4){0.f, 0.f, 0.f, 0.f};
            acc2[ms][eg] = (f32x4){0.f, 0.f, 0.f, 0.f};
        }

    // A prologue
    f32x4 acur[2][2];
    acur[0][0] = *reinterpret_cast<const f32x4*>(xrow0);
    acur[0][1] = *reinterpret_cast<const f32x4*>(xrow0 + 4);
    acur[1][0] = *reinterpret_cast<const f32x4*>(xrow1);
    acur[1][1] = *reinterpret_cast<const f32x4*>(xrow1 + 4);

#pragma unroll 1
    for (int s = 0; s < 16; ++s) {
        // B(s): 16 coalesced 16B/lane loads (L2-hot, single-buffered; TLP hides)
        half8 bh[8], bl[8];
#pragma unroll
        for (int eg = 0; eg < 8; ++eg) {
            bh[eg] = *reinterpret_cast<const half8*>(wqh + ((size_t)s * 8 + eg) * 512 + l * 8);
            bl[eg] = *reinterpret_cast<const half8*>(wql + ((size_t)s * 8 + eg) * 512 + l * 8);
        }

        // A(s+1) prefetch (HBM latency spans the MFMA block)
        f32x4 anxt[2][2];
        if (s + 1 < 16) {
            anxt[0][0] = *reinterpret_cast<const f32x4*>(xrow0 + (s + 1) * 32);
            anxt[0][1] = *reinterpret_cast<const f32x4*>(xrow0 + (s + 1) * 32 + 4);
            anxt[1][0] = *reinterpret_cast<const f32x4*>(xrow1 + (s + 1) * 32);
            anxt[1][1] = *reinterpret_cast<const f32x4*>(xrow1 + (s + 1) * 32 + 4);
        }

        // A(s) hi/lo split in-register
        half8 ah[2], al[2];
#pragma unroll
        for (int ms = 0; ms < 2; ++ms)
#pragma unroll
            for (int j = 0; j < 4; ++j) {
                const _Float16 h0 = (_Float16)acur[ms][0][j];
                const _Float16 h1 = (_Float16)acur[ms][1][j];
                ah[ms][j]     = h0;
                ah[ms][4 + j] = h1;
                al[ms][j]     = (_Float16)((acur[ms][0][j] - (float)h0) * LO_SCALE);
                al[ms][4 + j] = (_Float16)((acur[ms][1][j] - (float)h1) * LO_SCALE);
            }

        // 48 MFMA
#pragma unroll
        for (int eg = 0; eg < 8; ++eg)
#pragma unroll
            for (int ms = 0; ms < 2; ++ms) {
                acc[ms][eg]  = __builtin_amdgcn_mfma_f32_16x16x32_f16(ah[ms], bh[eg], acc[ms][eg],  0, 0, 0);
                acc2[ms][eg] = __builtin_amdgcn_mfma_f32_16x16x32_f16(ah[ms], bl[eg], acc2[ms][eg], 0, 0, 0);
                acc2[ms][eg] = __builtin_amdgcn_mfma_f32_16x16x32_f16(al[ms], bh[eg], acc2[ms][eg], 0, 0, 0);
            }

        if (s + 1 < 16) {
#pragma unroll
            for (int ms = 0; ms < 2; ++ms)
#pragma unroll
                for (int h = 0; h < 2; ++h)
                    acur[ms][h] = anxt[ms][h];
        }
    }

    // ---- cross-q reduction (1 barrier), fixed order = deterministic ----
#pragma unroll
    for (int ms = 0; ms < 2; ++ms)
#pragma unroll
        for (int eg = 0; eg < 8; ++eg)
            red[q][ms][eg][l] = acc[ms][eg] + acc2[ms][eg] * LO_INV;
    __syncthreads();

    const int ms_w = q >> 1;   // this wave's epilogue M-subtile (wave-uniform)
    f32x4 v[8];
#pragma unroll
    for (int eg = 0; eg < 8; ++eg) {
        f32x4 s0 = red[0][ms_w][eg][l];
        s0 += red[1][ms_w][eg][l];
        s0 += red[2][ms_w][eg][l];
        s0 += red[3][ms_w][eg][l];
        v[eg] = s0;
    }

    // ---- distributed epilogue (proven R7/R8): wave handles rows r0,r0+1 ----
    const int grp  = l >> 4;
    const int ln16 = l & 15;
    const int r0   = 2 * (q & 1);
    const float NEG = -__builtin_inff();

#pragma unroll
    for (int rr = 0; rr < 4; ++rr) {
        if (rr != r0 && rr != r0 + 1) continue;   // wave-uniform skip
        const int t = t0 + ms_w * 16 + 4 * grp + rr;
        float vr[8];
#pragma unroll
        for (int f = 0; f < 8; ++f) {
            vr[f] = v[f][rr];
            logits[(size_t)t * NEXP + 16 * f + ln16] = vr[f];
        }

        unsigned selm = 0u;
        int   mycand = 0;
        float mycv   = 0.0f;
#pragma unroll
        for (int k = 0; k < NCAND; ++k) {
            float lv = NEG; int le = 0;
#pragma unroll
            for (int f = 0; f < 8; ++f) {
                const float c = ((selm >> f) & 1u) ? NEG : vr[f];
                if (c > lv) { lv = c; le = 16 * f + ln16; }   // asc f => lower id on tie
            }
            float cv = lv; int ce = le;
#pragma unroll
            for (int off = 8; off > 0; off >>= 1) {
                const float ov = __shfl_xor(cv, off, 16);
                const int   oe = __shfl_xor(ce, off, 16);
                if (ov > cv || (ov == cv && oe < ce)) { cv = ov; ce = oe; }
            }
            if (ln16 == k) { mycand = ce; mycv = cv; }
            if ((ce & 15) == ln16) selm |= 1u << (ce >> 4);
        }

        // gap certification over ranks 0..8
        const float nv = __shfl(mycv, ln16 + 1, 16);
        int fl = (ln16 <= 8 && (mycv - nv) < DELTA_GAP) ? 1 : 0;
#pragma unroll
        for (int off = 8; off > 0; off >>= 1)
            fl |= __shfl_xor(fl, off, 16);

        // normalized top-8 probs (softmax denom cancels in renorm)
        const float m = __shfl(mycv, 0, 16);
        const float p = (ln16 < KSEL) ? expf(mycv - m) : 0.0f;
        float ps = p;
#pragma unroll
        for (int off = 8; off > 0; off >>= 1)
            ps += __shfl_xor(ps, off, 16);

        cand[(size_t)t * NCAND + ln16] = mycand;
        if (ln16 < KSEL) {
            topv[(size_t)t * KSEL + ln16] = p / ps;
            topi[(size_t)t * KSEL + ln16] = (float)mycand;
        }
        if (ln16 == 0) flag[t] = fl;
    }
}

// ===========================================================================
// Kernel 2: fp64 refine of flagged tokens (~250 expected at DELTA=1e-4).
// 4 independent partials per candidate (dep chain 32 -> 8); fixed combine
// order = deterministic.
// ===========================================================================
__global__ __launch_bounds__(256) void refine_flagged(
    const float* __restrict__ x, const float* __restrict__ w,
    const int* __restrict__ cand, const int* __restrict__ flag,
    float* __restrict__ topv, float* __restrict__ topi)
{
    const int l = threadIdx.x & 63;
    const int t = (int)((blockIdx.x * 256u + threadIdx.x) >> 6);
    if (!flag[t]) return;   // wave-uniform

    const int myid = cand[(size_t)t * NCAND + (l & 15)];
    const float* xrow = x + (size_t)t * HDIM;

    double xd[32];
#pragma unroll
    for (int i = 0; i < 8; ++i) {
        const f32x4 xv = *reinterpret_cast<const f32x4*>(xrow + i * 256 + l * 4);
#pragma unroll
        for (int j = 0; j < 4; ++j) xd[i * 4 + j] = (double)xv[j];
    }

    double part[NCAND];
    int    cid[NCAND];
#pragma unroll
    for (int c = 0; c < NCAND; ++c) {
        const int eid = __shfl(myid, c);
        cid[c] = eid;
        const float* wrow = w + (size_t)eid * HDIM;
        double s0 = 0.0, s1 = 0.0, s2 = 0.0, s3 = 0.0;   // 4 independent chains
#pragma unroll
        for (int i = 0; i < 8; ++i) {
            const f32x4 wv4 = *reinterpret_cast<const f32x4*>(wrow + i * 256 + l * 4);
            s0 = fma(xd[i * 4 + 0], (double)wv4[0], s0);
            s1 = fma(xd[i * 4 + 1], (double)wv4[1], s1);
            s2 = fma(xd[i * 4 + 2], (double)wv4[2], s2);
            s3 = fma(xd[i * 4 + 3], (double)wv4[3], s3);
        }
        part[c] = (s0 + s1) + (s2 + s3);
    }

#pragma unroll
    for (int off = 32; off > 0; off >>= 1)
#pragma unroll
        for (int c = 0; c < NCAND; ++c)
            part[c] += __shfl_xor(part[c], off);

    unsigned selm = 0u;
    double m = 0.0, kv = 0.0;
    int ki = 0;
    float psum = 0.0f;
#pragma unroll
    for (int k = 0; k < KSEL; ++k) {
        double bv = -__builtin_inf(); int bi = 0x7fffffff; int bc = 0;
#pragma unroll
        for (int c = 0; c < NCAND; ++c) {
            if (!((selm >> c) & 1u)) {
                if (part[c] > bv || (part[c] == bv && cid[c] < bi)) {
                    bv = part[c]; bi = cid[c]; bc = c;
                }
            }
        }
        if (k == 0) m = bv;
        psum += expf((float)(bv - m));
        if (l == k) { kv = bv; ki = bi; }
        selm |= 1u << bc;
    }

    if (l < KSEL) {
        topv[(size_t)t * KSEL + l] = expf((float)(kv - m)) / psum;
        topi[(size_t)t * KSEL + l] = (float)ki;
    }
}

// ===========================================================================
// Fallback (ws too small): proven round-2 fused fp64 kernel.
// ===========================================================================
#define BM 64
#define BK 32
#define BSTRIDE (BK + 4)
__global__ __launch_bounds__(256) void router_fused(
    const float* __restrict__ x, const float* __restrict__ w,
    float* __restrict__ logits, float* __restrict__ topv, float* __restrict__ topi)
{
    __shared__ float Bs[NEXP][BSTRIDE];
    const int tid = threadIdx.x;
    const int tn = tid & 15, tm = tid >> 4;
    const int row0 = blockIdx.x * BM;
    const int kc = tid & 7, cr = tid >> 3;

    double acc[4][8];
#pragma unroll
    for (int i = 0; i < 4; ++i)
#pragma unroll
        for (int j = 0; j < 8; ++j) acc[i][j] = 0.0;

    const float* xp[4];
#pragma unroll
    for (int i = 0; i < 4; ++i) xp[i] = x + (size_t)(row0 + tm + 16 * i) * HDIM;

    float4 rb[4];
#pragma unroll
    for (int p = 0; p < 4; ++p)
        rb[p] = *reinterpret_cast<const float4*>(&w[(size_t)(cr + 32 * p) * HDIM + kc * 4]);

    for (int k0 = 0; k0 < HDIM; k0 += BK) {
        __syncthreads();
#pragma unroll
        for (int p = 0; p < 4; ++p)
            *reinterpret_cast<float4*>(&Bs[cr + 32 * p][kc * 4]) = rb[p];
        __syncthreads();
        if (k0 + BK < HDIM) {
#pragma unroll
            for (int p = 0; p < 4; ++p)
                rb[p] = *reinterpret_cast<const float4*>(
                    &w[(size_t)(cr + 32 * p) * HDIM + (k0 + BK) + kc * 4]);
        }
#pragma unroll 4
        for (int k4 = 0; k4 < BK; k4 += 4) {
            float4 a4[4], b4[8];
#pragma unroll
            for (int i = 0; i < 4; ++i)
                a4[i] = *reinterpret_cast<const float4*>(&xp[i][k0 + k4]);
#pragma unroll
            for (int j = 0; j < 8; ++j)
                b4[j] = *reinterpret_cast<const float4*>(&Bs[tn + 16 * j][k4]);
#pragma unroll
            for (int kk = 0; kk < 4; ++kk) {
                double bd[8];
#pragma unroll
                for (int j = 0; j < 8; ++j) bd[j] = (double)((const float*)&b4[j])[kk];
#pragma unroll
                for (int i = 0; i < 4; ++i) {
                    const double ad = (double)((const float*)&a4[i])[kk];
#pragma unroll
                    for (int j = 0; j < 8; ++j) acc[i][j] = fma(ad, bd[j], acc[i][j]);
                }
            }
        }
    }
#pragma unroll
    for (int i = 0; i < 4; ++i) {
        float* orow = logits + (size_t)(row0 + tm + 16 * i) * NEXP;
#pragma unroll
        for (int j = 0; j < 8; ++j) orow[tn + 16 * j] = (float)acc[i][j];
    }
    for (int i = 0; i < 4; ++i) {
        const int t = row0 + tm + 16 * i;
        unsigned sel = 0u;
        double m = 0.0, kv = 0.0;
        int ki = 0;
        const double NEGD = -__builtin_inf();
#pragma unroll
        for (int k = 0; k < KSEL; ++k) {
            double lv = NEGD; int le = 0;
#pragma unroll
            for (int j = 0; j < 8; ++j) {
                const double v = (sel >> j) & 1u ? NEGD : acc[i][j];
                if (v > lv) { lv = v; le = tn + 16 * j; }
            }
            double cv = lv; int ce = le;
#pragma unroll
            for (int off = 8; off > 0; off >>= 1) {
                const double ov = __shfl_xor(cv, off, 16);
                const int    oe = __shfl_xor(ce, off, 16);
                if (ov > cv || (ov == cv && oe < ce)) { cv = ov; ce = oe; }
            }
            if (k == 0) m = cv;
            if (tn == k) { kv = cv; ki = ce; }
            if ((ce & 15) == tn) sel |= 1u << (ce >> 4);
        }
        float z = 0.0f;
#pragma unroll
        for (int j = 0; j < 8; ++j) z += expf((float)(acc[i][j] - m));
#pragma unroll
        for (int off = 8; off > 0; off >>= 1) z += __shfl_xor(z, off, 16);
        const float p = (tn < KSEL) ? expf((float)(kv - m)) / z : 0.0f;
        float ps = p;
#pragma unroll
        for (int off = 8; off > 0; off >>= 1) ps += __shfl_xor(ps, off, 16);
        if (tn < KSEL) {
            topv[(size_t)t * KSEL + tn] = p / ps;
            topi[(size_t)t * KSEL + tn] = (float)ki;
        }
    }
}

extern "C" void kernel_launch(void* const* d_in, const int* in_sizes, int n_in,
                              void* d_out, int out_size, void* d_ws, size_t ws_size,
                              hipStream_t stream) {
    const float* x = (const float*)d_in[0];   // [16384, 2048]
    const float* w = (const float*)d_in[1];   // [128, 2048]

    float* out    = (float*)d_out;
    float* logits = out;                                   // 16384*128
    float* topv   = out + (size_t)NTOK * NEXP;             // 16384*8
    float* topi   = topv + (size_t)NTOK * KSEL;            // 16384*8

    // ws layout: whp[512KB] | wlp[512KB] | cand[1MB] | flag[64KB]
    const size_t plane = (size_t)NEXP * HDIM;              // 262144 halfwords
    const size_t need  = plane * 2 * sizeof(_Float16)
                       + (size_t)NTOK * NCAND * sizeof(int)
                       + (size_t)NTOK * sizeof(int);
    if (ws_size >= need) {
        _Float16* whp = (_Float16*)d_ws;
        _Float16* wlp = whp + plane;
        int* cand = (int*)(wlp + plane);
        int* flag = cand + (size_t)NTOK * NCAND;
        w_convert<<<NEXP, 256, 0, stream>>>(w, whp, wlp);
        gemm3_nolds<<<NTOK / 32, 256, 0, stream>>>(x, whp, wlp, logits, topv, topi, cand, flag);
        refine_flagged<<<NTOK / 4, 256, 0, stream>>>(x, w, cand, flag, topv, topi);
    } else {
        router_fused<<<NTOK / BM, 256, 0, stream>>>(x, w, logits, topv, topi);
    }
}